// Round 6
// baseline (89.334 us; speedup 1.0000x reference)
//
#include <hip/hip_runtime.h>

// GPUTimeMask: x (B=64, C=16, T=60000) fp32; starts/widths (NUM_MASKS=2, B) int32.
// Zero x[b, :, t] for t in [start, start+clip(width,1,150)) for each of 2 masks.
//
// Single fused kernel: exact-mapping nontemporal float4 copy (2000 blk x 256
// thr x 30 float4, no tail; 122 KB per direction per block to amortize DRAM
// read<->write turnaround), then per-block in-place zeroing of mask-span
// overlap. A block's 7680-float4 range spans at most 2 rows; overlap check is
// uniform and ~96% of blocks skip it.

#define B_DIM 64
#define C_DIM 16
#define T_DIM 60000
#define MAXW 150
#define NUM_MASKS 2

#define ROW4 (T_DIM / 4)                        // 15000 float4 per row
#define TOTAL4 (B_DIM * C_DIM * ROW4)           // 15,360,000 float4
#define NBLK 2000
#define NTHR 256
#define K_ITER (TOTAL4 / (NBLK * NTHR))         // 30, exact
#define BLK4 (NTHR * K_ITER)                    // 7680 float4 per block

typedef __attribute__((ext_vector_type(4))) float f32x4;

__global__ __launch_bounds__(NTHR) void GPUTimeMask_38010460570421_fused(
    const f32x4* __restrict__ src,
    f32x4* __restrict__ dst,
    const int* __restrict__ starts,   // (2, B) flat
    const int* __restrict__ widths) { // (2, B) flat
    int tid = threadIdx.x;
    int f0 = blockIdx.x * BLK4;       // block's first float4 (flat)
    int f1 = f0 + BLK4;               // exclusive

    // ---- hot copy loop: 30 nt loads batched, then 30 nt stores ----
    const f32x4* __restrict__ s = src + f0 + tid;
    f32x4* __restrict__ d = dst + f0 + tid;
    f32x4 v[K_ITER];
    #pragma unroll
    for (int k = 0; k < K_ITER; ++k) {
        v[k] = __builtin_nontemporal_load(&s[k * NTHR]);
    }
    #pragma unroll
    for (int k = 0; k < K_ITER; ++k) {
        __builtin_nontemporal_store(v[k], &d[k * NTHR]);
    }

    // ---- fixup: zero mask-span overlap within this block's range ----
    // Block range spans at most 2 rows (BLK4 < ROW4).
    int r0 = f0 / ROW4;               // const divisor -> magic mul
    int r1 = (f1 - 1) / ROW4;

    bool need = false;
    #pragma unroll 2
    for (int r = r0; r <= r1; ++r) {
        int b = r >> 4;               // r = b*16 + c
        int lo = max(f0, r * ROW4) * 4 - r * T_DIM;       // row-local float lo
        int hi = min(f1, (r + 1) * ROW4) * 4 - r * T_DIM; // row-local float hi
        #pragma unroll
        for (int m = 0; m < NUM_MASKS; ++m) {
            int sp = starts[m * B_DIM + b];
            int w  = widths[m * B_DIM + b];
            w = min(max(w, 1), MAXW);
            need |= (max(sp, lo) < min(sp + w, hi));
        }
    }
    if (!need) return;

    __syncthreads();                  // drain copy stores before re-storing

    float* outf = (float*)dst;
    #pragma unroll 2
    for (int r = r0; r <= r1; ++r) {
        int b = r >> 4;
        int lo = max(f0, r * ROW4) * 4 - r * T_DIM;
        int hi = min(f1, (r + 1) * ROW4) * 4 - r * T_DIM;
        long rowbase = (long)r * T_DIM;
        #pragma unroll
        for (int m = 0; m < NUM_MASKS; ++m) {
            int sp = starts[m * B_DIM + b];
            int w  = widths[m * B_DIM + b];
            w = min(max(w, 1), MAXW);
            int a = max(sp, lo);
            int e = min(sp + w, hi);
            for (int t = a + tid; t < e; t += NTHR) {
                outf[rowbase + t] = 0.0f;
            }
        }
    }
}

extern "C" void kernel_launch(void* const* d_in, const int* in_sizes, int n_in,
                              void* d_out, int out_size, void* d_ws, size_t ws_size,
                              hipStream_t stream) {
    const f32x4* x = (const f32x4*)d_in[0];
    const int* starts = (const int*)d_in[1];
    const int* widths = (const int*)d_in[2];

    hipLaunchKernelGGL(GPUTimeMask_38010460570421_fused,
                       dim3(NBLK), dim3(NTHR), 0, stream,
                       x, (f32x4*)d_out, starts, widths);
}

// Round 7
// 85.338 us; speedup vs baseline: 1.0468x; 1.0468x over previous
//
#include <hip/hip_runtime.h>

// GPUTimeMask: x (B=64, C=16, T=60000) fp32; starts/widths (NUM_MASKS=2, B) int32.
// Zero x[b, :, t] for t in [start, start+clip(width,1,150)) for each of 2 masks.
//
// Single fused kernel: exact-mapping nontemporal float4 copy (6000 blk x 256
// thr x 10 float4, no tail; more independent blocks -> denser DRAM request
// queues), then per-block in-place zeroing of mask-span overlap. A block's
// 2560-float4 range spans at most 2 rows; overlap check is uniform and ~95%
// of blocks skip it.

#define B_DIM 64
#define C_DIM 16
#define T_DIM 60000
#define MAXW 150
#define NUM_MASKS 2

#define ROW4 (T_DIM / 4)                        // 15000 float4 per row
#define TOTAL4 (B_DIM * C_DIM * ROW4)           // 15,360,000 float4
#define NBLK 6000
#define NTHR 256
#define K_ITER (TOTAL4 / (NBLK * NTHR))         // 10, exact
#define BLK4 (NTHR * K_ITER)                    // 2560 float4 per block

typedef __attribute__((ext_vector_type(4))) float f32x4;

__global__ __launch_bounds__(NTHR) void GPUTimeMask_38010460570421_fused(
    const f32x4* __restrict__ src,
    f32x4* __restrict__ dst,
    const int* __restrict__ starts,   // (2, B) flat
    const int* __restrict__ widths) { // (2, B) flat
    int tid = threadIdx.x;
    int f0 = blockIdx.x * BLK4;       // block's first float4 (flat)
    int f1 = f0 + BLK4;               // exclusive

    // ---- hot copy loop: 10 nt loads batched, then 10 nt stores ----
    const f32x4* __restrict__ s = src + f0 + tid;
    f32x4* __restrict__ d = dst + f0 + tid;
    f32x4 v[K_ITER];
    #pragma unroll
    for (int k = 0; k < K_ITER; ++k) {
        v[k] = __builtin_nontemporal_load(&s[k * NTHR]);
    }
    #pragma unroll
    for (int k = 0; k < K_ITER; ++k) {
        __builtin_nontemporal_store(v[k], &d[k * NTHR]);
    }

    // ---- fixup: zero mask-span overlap within this block's range ----
    // Block range spans at most 2 rows (BLK4 < ROW4).
    int r0 = f0 / ROW4;               // const divisor -> magic mul
    int r1 = (f1 - 1) / ROW4;

    bool need = false;
    #pragma unroll 2
    for (int r = r0; r <= r1; ++r) {
        int b = r >> 4;               // r = b*16 + c
        int lo = max(f0, r * ROW4) * 4 - r * T_DIM;       // row-local float lo
        int hi = min(f1, (r + 1) * ROW4) * 4 - r * T_DIM; // row-local float hi
        #pragma unroll
        for (int m = 0; m < NUM_MASKS; ++m) {
            int sp = starts[m * B_DIM + b];
            int w  = widths[m * B_DIM + b];
            w = min(max(w, 1), MAXW);
            need |= (max(sp, lo) < min(sp + w, hi));
        }
    }
    if (!need) return;

    __syncthreads();                  // drain copy stores before re-storing

    float* outf = (float*)dst;
    #pragma unroll 2
    for (int r = r0; r <= r1; ++r) {
        int b = r >> 4;
        int lo = max(f0, r * ROW4) * 4 - r * T_DIM;
        int hi = min(f1, (r + 1) * ROW4) * 4 - r * T_DIM;
        long rowbase = (long)r * T_DIM;
        #pragma unroll
        for (int m = 0; m < NUM_MASKS; ++m) {
            int sp = starts[m * B_DIM + b];
            int w  = widths[m * B_DIM + b];
            w = min(max(w, 1), MAXW);
            int a = max(sp, lo);
            int e = min(sp + w, hi);
            for (int t = a + tid; t < e; t += NTHR) {
                outf[rowbase + t] = 0.0f;
            }
        }
    }
}

extern "C" void kernel_launch(void* const* d_in, const int* in_sizes, int n_in,
                              void* d_out, int out_size, void* d_ws, size_t ws_size,
                              hipStream_t stream) {
    const f32x4* x = (const f32x4*)d_in[0];
    const int* starts = (const int*)d_in[1];
    const int* widths = (const int*)d_in[2];

    hipLaunchKernelGGL(GPUTimeMask_38010460570421_fused,
                       dim3(NBLK), dim3(NTHR), 0, stream,
                       x, (f32x4*)d_out, starts, widths);
}

// Round 8
// 82.339 us; speedup vs baseline: 1.0850x; 1.0364x over previous
//
#include <hip/hip_runtime.h>

// GPUTimeMask: x (B=64, C=16, T=60000) fp32; starts/widths (NUM_MASKS=2, B) int32.
// Zero x[b, :, t] for t in [start, start+clip(width,1,150)) for each of 2 masks.
//
// Single fused kernel: exact-mapping nontemporal float4 copy (12000 blk x 256
// thr x 5 float4, no tail; many independent blocks -> densely interleaved
// DRAM request queues), then per-block in-place zeroing of mask-span overlap.
// A block's 1280-float4 range spans at most 2 rows; overlap check is uniform
// and ~97% of blocks skip it.

#define B_DIM 64
#define C_DIM 16
#define T_DIM 60000
#define MAXW 150
#define NUM_MASKS 2

#define ROW4 (T_DIM / 4)                        // 15000 float4 per row
#define TOTAL4 (B_DIM * C_DIM * ROW4)           // 15,360,000 float4
#define NBLK 12000
#define NTHR 256
#define K_ITER (TOTAL4 / (NBLK * NTHR))         // 5, exact
#define BLK4 (NTHR * K_ITER)                    // 1280 float4 per block

typedef __attribute__((ext_vector_type(4))) float f32x4;

__global__ __launch_bounds__(NTHR) void GPUTimeMask_38010460570421_fused(
    const f32x4* __restrict__ src,
    f32x4* __restrict__ dst,
    const int* __restrict__ starts,   // (2, B) flat
    const int* __restrict__ widths) { // (2, B) flat
    int tid = threadIdx.x;
    int f0 = blockIdx.x * BLK4;       // block's first float4 (flat)
    int f1 = f0 + BLK4;               // exclusive

    // ---- hot copy loop: 5 nt loads batched, then 5 nt stores ----
    const f32x4* __restrict__ s = src + f0 + tid;
    f32x4* __restrict__ d = dst + f0 + tid;
    f32x4 v[K_ITER];
    #pragma unroll
    for (int k = 0; k < K_ITER; ++k) {
        v[k] = __builtin_nontemporal_load(&s[k * NTHR]);
    }
    #pragma unroll
    for (int k = 0; k < K_ITER; ++k) {
        __builtin_nontemporal_store(v[k], &d[k * NTHR]);
    }

    // ---- fixup: zero mask-span overlap within this block's range ----
    // Block range spans at most 2 rows (BLK4 < ROW4).
    int r0 = f0 / ROW4;               // const divisor -> magic mul
    int r1 = (f1 - 1) / ROW4;

    bool need = false;
    #pragma unroll 2
    for (int r = r0; r <= r1; ++r) {
        int b = r >> 4;               // r = b*16 + c
        int lo = max(f0, r * ROW4) * 4 - r * T_DIM;       // row-local float lo
        int hi = min(f1, (r + 1) * ROW4) * 4 - r * T_DIM; // row-local float hi
        #pragma unroll
        for (int m = 0; m < NUM_MASKS; ++m) {
            int sp = starts[m * B_DIM + b];
            int w  = widths[m * B_DIM + b];
            w = min(max(w, 1), MAXW);
            need |= (max(sp, lo) < min(sp + w, hi));
        }
    }
    if (!need) return;

    __syncthreads();                  // drain copy stores before re-storing

    float* outf = (float*)dst;
    #pragma unroll 2
    for (int r = r0; r <= r1; ++r) {
        int b = r >> 4;
        int lo = max(f0, r * ROW4) * 4 - r * T_DIM;
        int hi = min(f1, (r + 1) * ROW4) * 4 - r * T_DIM;
        long rowbase = (long)r * T_DIM;
        #pragma unroll
        for (int m = 0; m < NUM_MASKS; ++m) {
            int sp = starts[m * B_DIM + b];
            int w  = widths[m * B_DIM + b];
            w = min(max(w, 1), MAXW);
            int a = max(sp, lo);
            int e = min(sp + w, hi);
            for (int t = a + tid; t < e; t += NTHR) {
                outf[rowbase + t] = 0.0f;
            }
        }
    }
}

extern "C" void kernel_launch(void* const* d_in, const int* in_sizes, int n_in,
                              void* d_out, int out_size, void* d_ws, size_t ws_size,
                              hipStream_t stream) {
    const f32x4* x = (const f32x4*)d_in[0];
    const int* starts = (const int*)d_in[1];
    const int* widths = (const int*)d_in[2];

    hipLaunchKernelGGL(GPUTimeMask_38010460570421_fused,
                       dim3(NBLK), dim3(NTHR), 0, stream,
                       x, (f32x4*)d_out, starts, widths);
}